// Round 1
// baseline (1143.847 us; speedup 1.0000x reference)
//
#include <hip/hip_runtime.h>
#include <hip/hip_bf16.h>

#define EMBED   1024
#define EMBED3  3072
#define HEADS   16
#define DHEAD   64
#define SEQ     2048
#define BATCH   2
#define NTOK    4096            // BATCH*SEQ
#define ATT_SCALE 0.125f        // 64^-0.5

// ---------------- GEMM: C[M,N] = A[M,1024] @ W[1024,N] + bias ----------------
// 128x128 tile, BK=8, 256 threads, 8x8 per thread (2x2 blocks of 4x4).
// mode 0: plain store to P0[m*N + c]
// mode 1: QKV scatter -> P0=Q (scaled), P1=K, P2=V in (b,h,s,dh) layout
#define BM 128
#define BN 128
#define BKK 8

__global__ __launch_bounds__(256, 2)
void gemm_kernel(const float* __restrict__ A, const float* __restrict__ W,
                 const float* __restrict__ bias, int N, int mode,
                 float* __restrict__ P0, float* __restrict__ P1, float* __restrict__ P2)
{
    __shared__ float As[BKK][BM + 4];   // As[k][m], padded vs bank conflicts
    __shared__ float Bs[BKK][BN + 4];   // Bs[k][n]

    const int tid = threadIdx.x;
    const int tx = tid & 15;
    const int ty = tid >> 4;
    const int m0 = blockIdx.y * BM;
    const int n0 = blockIdx.x * BN;

    float acc[8][8];
#pragma unroll
    for (int i = 0; i < 8; ++i)
#pragma unroll
        for (int j = 0; j < 8; ++j) acc[i][j] = 0.f;

    // A tile load: 128x8 floats, one float4 along k per thread
    const int a_m = tid >> 1;            // 0..127
    const int a_k = (tid & 1) << 2;      // 0 or 4
    // B tile load: 8x128 floats, one float4 along n per thread
    const int b_k = tid >> 5;            // 0..7
    const int b_n = (tid & 31) << 2;     // 0..124

    const float* Aptr = A + (size_t)(m0 + a_m) * EMBED + a_k;
    const float* Bptr = W + (size_t)b_k * N + n0 + b_n;

    for (int k0 = 0; k0 < EMBED; k0 += BKK) {
        float4 av = *reinterpret_cast<const float4*>(Aptr + k0);
        float4 bv = *reinterpret_cast<const float4*>(Bptr + (size_t)k0 * N);
        As[a_k + 0][a_m] = av.x;
        As[a_k + 1][a_m] = av.y;
        As[a_k + 2][a_m] = av.z;
        As[a_k + 3][a_m] = av.w;
        *reinterpret_cast<float4*>(&Bs[b_k][b_n]) = bv;
        __syncthreads();
#pragma unroll
        for (int k = 0; k < BKK; ++k) {
            float a[8], b[8];
            *reinterpret_cast<float4*>(&a[0]) = *reinterpret_cast<const float4*>(&As[k][ty * 4]);
            *reinterpret_cast<float4*>(&a[4]) = *reinterpret_cast<const float4*>(&As[k][64 + ty * 4]);
            *reinterpret_cast<float4*>(&b[0]) = *reinterpret_cast<const float4*>(&Bs[k][tx * 4]);
            *reinterpret_cast<float4*>(&b[4]) = *reinterpret_cast<const float4*>(&Bs[k][64 + tx * 4]);
#pragma unroll
            for (int i = 0; i < 8; ++i)
#pragma unroll
                for (int j = 0; j < 8; ++j) acc[i][j] = fmaf(a[i], b[j], acc[i][j]);
        }
        __syncthreads();
    }

    // epilogue
#pragma unroll
    for (int rh = 0; rh < 2; ++rh) {
#pragma unroll
        for (int i = 0; i < 4; ++i) {
            const int m = m0 + rh * 64 + ty * 4 + i;
#pragma unroll
            for (int ch = 0; ch < 2; ++ch) {
                const int c0 = n0 + ch * 64 + tx * 4;
                float4 o;
                o.x = acc[rh * 4 + i][ch * 4 + 0] + bias[c0 + 0];
                o.y = acc[rh * 4 + i][ch * 4 + 1] + bias[c0 + 1];
                o.z = acc[rh * 4 + i][ch * 4 + 2] + bias[c0 + 2];
                o.w = acc[rh * 4 + i][ch * 4 + 3] + bias[c0 + 3];
                if (mode == 0) {
                    *reinterpret_cast<float4*>(&P0[(size_t)m * N + c0]) = o;
                } else {
                    const int t = c0 >> 10;            // 0:q 1:k 2:v
                    const int h = (c0 & 1023) >> 6;
                    const int d = c0 & 63;
                    const int bb = m >> 11;            // /SEQ
                    const int s = m & 2047;
                    if (t == 0) { o.x *= ATT_SCALE; o.y *= ATT_SCALE; o.z *= ATT_SCALE; o.w *= ATT_SCALE; }
                    float* dst = (t == 0) ? P0 : (t == 1) ? P1 : P2;
                    *reinterpret_cast<float4*>(
                        &dst[(((size_t)bb * HEADS + h) * SEQ + s) * DHEAD + d]) = o;
                }
            }
        }
    }
}

// ---------------- Flash attention: per (b,h), 64-row Q tiles ----------------
// Q pre-scaled. Streams K/V in 64-row tiles; online softmax in registers.
__global__ __launch_bounds__(256, 2)
void attn_kernel(const float* __restrict__ Q, const float* __restrict__ K,
                 const float* __restrict__ V, float* __restrict__ AO)
{
    __shared__ float Qs[64][68];   // [d][r] transposed
    __shared__ float Ks[64][68];   // [d][c] transposed
    __shared__ float Vs[64][68];   // [c][d] natural
    __shared__ float Ps[64][68];   // [c][r] P transposed

    const int tid = threadIdx.x;
    const int tx = tid & 15;
    const int ty = tid >> 4;
    const int bh = blockIdx.y;               // 0..31 = b*HEADS+h
    const int q0 = blockIdx.x * 64;

    const float* Qbase = Q + ((size_t)bh * SEQ + q0) * DHEAD;
    const float* Kbase = K + (size_t)bh * SEQ * DHEAD;
    const float* Vbase = V + (size_t)bh * SEQ * DHEAD;

    // load Q tile transposed
#pragma unroll
    for (int rep = 0; rep < 4; ++rep) {
        const int idx = rep * 256 + tid;
        const int r = idx >> 4;
        const int d4 = (idx & 15) << 2;
        float4 v = *reinterpret_cast<const float4*>(Qbase + (size_t)r * DHEAD + d4);
        Qs[d4 + 0][r] = v.x; Qs[d4 + 1][r] = v.y; Qs[d4 + 2][r] = v.z; Qs[d4 + 3][r] = v.w;
    }

    float o[4][4];
    float m_i[4], l_i[4];
#pragma unroll
    for (int i = 0; i < 4; ++i) {
        m_i[i] = -1e30f; l_i[i] = 0.f;
#pragma unroll
        for (int j = 0; j < 4; ++j) o[i][j] = 0.f;
    }

    for (int kv0 = 0; kv0 < SEQ; kv0 += 64) {
        __syncthreads();   // also covers Qs on first iter; protects Ks/Vs/Ps reuse after
        // load K tile (transposed) + V tile (natural)
#pragma unroll
        for (int rep = 0; rep < 4; ++rep) {
            const int idx = rep * 256 + tid;
            const int r = idx >> 4;
            const int d4 = (idx & 15) << 2;
            float4 kv = *reinterpret_cast<const float4*>(Kbase + (size_t)(kv0 + r) * DHEAD + d4);
            Ks[d4 + 0][r] = kv.x; Ks[d4 + 1][r] = kv.y; Ks[d4 + 2][r] = kv.z; Ks[d4 + 3][r] = kv.w;
            float4 vv = *reinterpret_cast<const float4*>(Vbase + (size_t)(kv0 + r) * DHEAD + d4);
            *reinterpret_cast<float4*>(&Vs[r][d4]) = vv;
        }
        __syncthreads();

        // S = (Q*scale) K^T  -- 4x4 per thread
        float s[4][4];
#pragma unroll
        for (int i = 0; i < 4; ++i)
#pragma unroll
            for (int j = 0; j < 4; ++j) s[i][j] = 0.f;
        for (int d = 0; d < 64; ++d) {
            float a[4], b[4];
            *reinterpret_cast<float4*>(a) = *reinterpret_cast<const float4*>(&Qs[d][ty * 4]);
            *reinterpret_cast<float4*>(b) = *reinterpret_cast<const float4*>(&Ks[d][tx * 4]);
#pragma unroll
            for (int i = 0; i < 4; ++i)
#pragma unroll
                for (int j = 0; j < 4; ++j) s[i][j] = fmaf(a[i], b[j], s[i][j]);
        }

        // online softmax; row r = q0 + ty*4 + i spans 16 lanes (tx = lane&15)
#pragma unroll
        for (int i = 0; i < 4; ++i) {
            float mt = fmaxf(fmaxf(s[i][0], s[i][1]), fmaxf(s[i][2], s[i][3]));
#pragma unroll
            for (int mk = 1; mk < 16; mk <<= 1)
                mt = fmaxf(mt, __shfl_xor(mt, mk, 64));
            const float m_new = fmaxf(m_i[i], mt);
            const float alpha = __expf(m_i[i] - m_new);
            float psum = 0.f;
#pragma unroll
            for (int j = 0; j < 4; ++j) { s[i][j] = __expf(s[i][j] - m_new); psum += s[i][j]; }
#pragma unroll
            for (int mk = 1; mk < 16; mk <<= 1)
                psum += __shfl_xor(psum, mk, 64);
            l_i[i] = l_i[i] * alpha + psum;
            m_i[i] = m_new;
#pragma unroll
            for (int j = 0; j < 4; ++j) o[i][j] *= alpha;
        }

        // stage P^T into LDS: Ps[c][r]
#pragma unroll
        for (int j = 0; j < 4; ++j) {
            float4 pv = make_float4(s[0][j], s[1][j], s[2][j], s[3][j]);
            *reinterpret_cast<float4*>(&Ps[tx * 4 + j][ty * 4]) = pv;
        }
        __syncthreads();

        // O += P @ V
        for (int c = 0; c < 64; ++c) {
            float a[4], b[4];
            *reinterpret_cast<float4*>(a) = *reinterpret_cast<const float4*>(&Ps[c][ty * 4]);
            *reinterpret_cast<float4*>(b) = *reinterpret_cast<const float4*>(&Vs[c][tx * 4]);
#pragma unroll
            for (int i = 0; i < 4; ++i)
#pragma unroll
                for (int j = 0; j < 4; ++j) o[i][j] = fmaf(a[i], b[j], o[i][j]);
        }
    }

    // normalize + store to (b, s, h*64+d) layout
    const int bb = bh >> 4;   // bh = b*HEADS + h
    const int h = bh & 15;
#pragma unroll
    for (int i = 0; i < 4; ++i) {
        const int r = q0 + ty * 4 + i;
        const float inv = 1.f / l_i[i];
        float4 ov = make_float4(o[i][0] * inv, o[i][1] * inv, o[i][2] * inv, o[i][3] * inv);
        *reinterpret_cast<float4*>(
            &AO[((size_t)bb * SEQ + r) * EMBED + h * DHEAD + tx * 4]) = ov;
    }
}

// ---------------- launch ----------------
extern "C" void kernel_launch(void* const* d_in, const int* in_sizes, int n_in,
                              void* d_out, int out_size, void* d_ws, size_t ws_size,
                              hipStream_t stream)
{
    const float* x     = (const float*)d_in[0];
    const float* w_qkv = (const float*)d_in[1];
    const float* b_qkv = (const float*)d_in[2];
    const float* w_out = (const float*)d_in[3];
    const float* b_out = (const float*)d_in[4];
    float* out = (float*)d_out;

    // workspace: Q | K | V | AO, each NTOK*EMBED fp32 (16 MB) -> 64 MB total
    float* Q  = (float*)d_ws;
    float* K  = Q + (size_t)NTOK * EMBED;
    float* V  = K + (size_t)NTOK * EMBED;
    float* AO = V + (size_t)NTOK * EMBED;

    dim3 blk(256);

    // 1) QKV projection + bias + scale + head-layout scatter
    gemm_kernel<<<dim3(EMBED3 / BN, NTOK / BM), blk, 0, stream>>>(
        x, w_qkv, b_qkv, EMBED3, 1, Q, K, V);

    // 2) flash attention per (b,h), 64-row q tiles
    attn_kernel<<<dim3(SEQ / 64, BATCH * HEADS), blk, 0, stream>>>(Q, K, V, AO);

    // 3) output projection
    gemm_kernel<<<dim3(EMBED / BN, NTOK / BM), blk, 0, stream>>>(
        AO, w_out, b_out, EMBED, 0, out, nullptr, nullptr);
}

// Round 3
// 240.904 us; speedup vs baseline: 4.7481x; 4.7481x over previous
//
#include <hip/hip_runtime.h>

#define EMBED  1024
#define HEADS  16
#define DHEAD  64
#define SEQ    2048
#define BATCH  2
#define NTOK   4096
#define QSCALE 0.125f

typedef unsigned short u16t;
typedef float f32x4 __attribute__((ext_vector_type(4)));
typedef __bf16 bf16x8 __attribute__((ext_vector_type(8)));
typedef u16t u16x8 __attribute__((ext_vector_type(8)));
typedef u16t u16x4 __attribute__((ext_vector_type(4)));

static __device__ __forceinline__ u16t f2bf(float f) {
    unsigned u = __builtin_bit_cast(unsigned, f);
    return (u16t)((u + 0x7fffu + ((u >> 16) & 1u)) >> 16);   // RNE
}
static __device__ __forceinline__ bf16x8 asbf(u16x8 v) {
    return __builtin_bit_cast(bf16x8, v);
}
static __device__ __forceinline__ f32x4 mfma16(bf16x8 a, bf16x8 b, f32x4 c) {
    return __builtin_amdgcn_mfma_f32_16x16x32_bf16(a, b, c, 0, 0, 0);
}

// ---------- x fp32 -> bf16 ----------
__global__ __launch_bounds__(256)
void xcvt(const float* __restrict__ X, u16t* __restrict__ XB)
{
    const size_t i = ((size_t)blockIdx.x * 256 + threadIdx.x) * 8;
    float4 a = *(const float4*)&X[i];
    float4 b = *(const float4*)&X[i + 4];
    u16x8 o;
    o[0] = f2bf(a.x); o[1] = f2bf(a.y); o[2] = f2bf(a.z); o[3] = f2bf(a.w);
    o[4] = f2bf(b.x); o[5] = f2bf(b.y); o[6] = f2bf(b.z); o[7] = f2bf(b.w);
    *(u16x8*)&XB[i] = o;
}

// ---------- W [K][N] fp32 -> WT [N][K] bf16 (64x64 LDS tiles) ----------
__global__ __launch_bounds__(256)
void wtrans(const float* __restrict__ W, u16t* __restrict__ WT, int K, int N)
{
    __shared__ float L[64][65];
    const int t = threadIdx.x;
    const int k0 = blockIdx.y * 64, n0 = blockIdx.x * 64;
#pragma unroll
    for (int rep = 0; rep < 4; ++rep) {
        const int id = rep * 256 + t;
        const int kk = id >> 4, nc = (id & 15) * 4;
        float4 v = *(const float4*)&W[(size_t)(k0 + kk) * N + n0 + nc];
        L[kk][nc] = v.x; L[kk][nc + 1] = v.y; L[kk][nc + 2] = v.z; L[kk][nc + 3] = v.w;
    }
    __syncthreads();
#pragma unroll
    for (int rep = 0; rep < 2; ++rep) {
        const int id = rep * 256 + t;
        const int n = id >> 3, kc = (id & 7) * 8;
        u16x8 o;
#pragma unroll
        for (int i = 0; i < 8; ++i) o[i] = f2bf(L[kc + i][n]);
        *(u16x8*)&WT[(size_t)(n0 + n) * K + k0 + kc] = o;
    }
}

// ---------- V (b,h,s,d) bf16 -> Vt (b,h,d,s) bf16 ----------
__global__ __launch_bounds__(256)
void vtrans(const u16t* __restrict__ V, u16t* __restrict__ Vt)
{
    __shared__ u16t L[64][65];
    const int t = threadIdx.x;
    const int bh = blockIdx.y;
    const int s0 = blockIdx.x * 64;
    const u16t* src = V + ((size_t)bh * SEQ + s0) * DHEAD;
#pragma unroll
    for (int rep = 0; rep < 2; ++rep) {
        const int id = rep * 256 + t;
        const int s = id >> 3, dc = (id & 7) * 8;
        u16x8 v = *(const u16x8*)&src[(size_t)s * DHEAD + dc];
#pragma unroll
        for (int i = 0; i < 8; ++i) L[s][dc + i] = v[i];
    }
    __syncthreads();
    u16t* dstb = Vt + (size_t)bh * DHEAD * SEQ + s0;
#pragma unroll
    for (int rep = 0; rep < 2; ++rep) {
        const int id = rep * 256 + t;
        const int d = id >> 3, sc = (id & 7) * 8;
        u16x8 o;
#pragma unroll
        for (int i = 0; i < 8; ++i) o[i] = L[sc + i][d];
        *(u16x8*)&dstb[(size_t)d * SEQ + sc] = o;
    }
}

// ---------- bf16 GEMM: C[M,N] = A[M,1024] @ WT[N,1024]^T + bias ----------
// mode 0: fp32 out to C0.  mode 1: QKV scatter -> bf16 Q(scaled)/K/V (b,h,s,d).
__global__ __launch_bounds__(256)
void gemm_bf16(const u16t* __restrict__ A, const u16t* __restrict__ BT,
               const float* __restrict__ bias, int N, int mode,
               float* __restrict__ C0, u16t* __restrict__ Qo,
               u16t* __restrict__ Ko, u16t* __restrict__ Vo)
{
    __shared__ __align__(16) u16t Al[128][72];
    __shared__ __align__(16) u16t Bl[128][72];
    const int t = threadIdx.x;
    const int lane = t & 63;
    const int g = lane >> 4, l15 = lane & 15;
    const int w = t >> 6, wr = w >> 1, wc = w & 1;
    const int m0 = blockIdx.y * 128, n0 = blockIdx.x * 128;
    const int srow = t >> 3, scol = (t & 7) * 8;

    f32x4 acc[4][4] = {};

    for (int k0 = 0; k0 < EMBED; k0 += 64) {
        __syncthreads();
#pragma unroll
        for (int rep = 0; rep < 4; ++rep) {
            const int row = rep * 32 + srow;
            *(u16x8*)&Al[row][scol] =
                *(const u16x8*)&A[(size_t)(m0 + row) * EMBED + k0 + scol];
            *(u16x8*)&Bl[row][scol] =
                *(const u16x8*)&BT[(size_t)(n0 + row) * EMBED + k0 + scol];
        }
        __syncthreads();
#pragma unroll
        for (int kk = 0; kk < 2; ++kk) {
            bf16x8 av[4], bv[4];
#pragma unroll
            for (int i = 0; i < 4; ++i) {
                av[i] = asbf(*(const u16x8*)&Al[wr * 64 + i * 16 + l15][kk * 32 + g * 8]);
                bv[i] = asbf(*(const u16x8*)&Bl[wc * 64 + i * 16 + l15][kk * 32 + g * 8]);
            }
#pragma unroll
            for (int i = 0; i < 4; ++i)
#pragma unroll
                for (int j = 0; j < 4; ++j)
                    acc[i][j] = mfma16(av[i], bv[j], acc[i][j]);
        }
    }

#pragma unroll
    for (int i = 0; i < 4; ++i)
#pragma unroll
        for (int j = 0; j < 4; ++j)
#pragma unroll
            for (int r = 0; r < 4; ++r) {
                const int row = m0 + wr * 64 + i * 16 + g * 4 + r;
                const int col = n0 + wc * 64 + j * 16 + l15;
                float v = acc[i][j][r] + bias[col];
                if (mode == 0) {
                    C0[(size_t)row * N + col] = v;
                } else {
                    const int tt = col >> 10, c1 = col & 1023;
                    const int h = c1 >> 6, d = c1 & 63;
                    const int b = row >> 11, s = row & 2047;
                    if (tt == 0) v *= QSCALE;
                    u16t* dst = (tt == 0) ? Qo : (tt == 1 ? Ko : Vo);
                    dst[(((size_t)b * HEADS + h) * SEQ + s) * DHEAD + d] = f2bf(v);
                }
            }
}

// ---------- MFMA flash attention ----------
// Per block: one (b,h), 64 q-rows; 4 waves x 16 q each.
// S^T = mfma(A=K, B=Q^T): lane holds S^T[key = mf*16+g*4+r][q = l15].
// Softmax per q-column: in-lane over 16 + shfl_xor(16,32).
// PV: A = P from registers (k-perm rename), B = V^T from LDS (two b64 reads).
__global__ __launch_bounds__(256)
void attn_mfma(const u16t* __restrict__ Q, const u16t* __restrict__ K,
               const u16t* __restrict__ Vt, u16t* __restrict__ AO)
{
    __shared__ __align__(16) u16t Kl[64][72];   // [key][d]
    __shared__ __align__(16) u16t Vl[64][72];   // [d][key]
    const int t = threadIdx.x;
    const int lane = t & 63, wq = t >> 6;
    const int g = lane >> 4, l15 = lane & 15;
    const int bh = blockIdx.y;
    const int q0 = blockIdx.x * 64;
    const int b = bh >> 4, h = bh & 15;

    const u16t* qrow = Q + ((size_t)bh * SEQ + q0 + wq * 16 + l15) * DHEAD;
    bf16x8 qf[2];
    qf[0] = asbf(*(const u16x8*)&qrow[g * 8]);
    qf[1] = asbf(*(const u16x8*)&qrow[32 + g * 8]);

    const int srow = t >> 3, scol = (t & 7) * 8;
    const u16t* Kb = K + (size_t)bh * SEQ * DHEAD;
    const u16t* Vb = Vt + (size_t)bh * DHEAD * SEQ;

    f32x4 accO[4] = {};
    float mrun = -1e30f, lrun = 0.f;

    for (int kv0 = 0; kv0 < SEQ; kv0 += 64) {
        __syncthreads();
#pragma unroll
        for (int rep = 0; rep < 2; ++rep) {
            const int r = rep * 32 + srow;
            *(u16x8*)&Kl[r][scol] = *(const u16x8*)&Kb[(size_t)(kv0 + r) * DHEAD + scol];
            *(u16x8*)&Vl[r][scol] = *(const u16x8*)&Vb[(size_t)r * SEQ + kv0 + scol];
        }
        __syncthreads();

        f32x4 s4[4] = {};
#pragma unroll
        for (int kk = 0; kk < 2; ++kk)
#pragma unroll
            for (int mf = 0; mf < 4; ++mf) {
                bf16x8 a = asbf(*(const u16x8*)&Kl[mf * 16 + l15][kk * 32 + g * 8]);
                s4[mf] = mfma16(a, qf[kk], s4[mf]);
            }

        float mt = s4[0][0];
#pragma unroll
        for (int mf = 0; mf < 4; ++mf)
#pragma unroll
            for (int r = 0; r < 4; ++r) mt = fmaxf(mt, s4[mf][r]);
        mt = fmaxf(mt, __shfl_xor(mt, 16));
        mt = fmaxf(mt, __shfl_xor(mt, 32));
        const float mnew = fmaxf(mrun, mt);
        const float alpha = __expf(mrun - mnew);
        mrun = mnew;

        float p[4][4]; float rs = 0.f;
#pragma unroll
        for (int mf = 0; mf < 4; ++mf)
#pragma unroll
            for (int r = 0; r < 4; ++r) { p[mf][r] = __expf(s4[mf][r] - mnew); rs += p[mf][r]; }
        rs += __shfl_xor(rs, 16);
        rs += __shfl_xor(rs, 32);
        lrun = lrun * alpha + rs;

        u16x8 pu[2];
#pragma unroll
        for (int kk = 0; kk < 2; ++kk)
#pragma unroll
            for (int j = 0; j < 8; ++j)
                pu[kk][j] = f2bf(p[kk * 2 + (j >> 2)][j & 3]);

        float al[4];
#pragma unroll
        for (int r = 0; r < 4; ++r) al[r] = __shfl(alpha, g * 4 + r);
#pragma unroll
        for (int nf = 0; nf < 4; ++nf)
#pragma unroll
            for (int r = 0; r < 4; ++r) accO[nf][r] *= al[r];

#pragma unroll
        for (int kk = 0; kk < 2; ++kk)
#pragma unroll
            for (int nf = 0; nf < 4; ++nf) {
                const u16t* vr = &Vl[nf * 16 + l15][0];
                u16x4 lo = *(const u16x4*)&vr[kk * 32 + g * 4];
                u16x4 hi = *(const u16x4*)&vr[kk * 32 + 16 + g * 4];
                u16x8 bb = __builtin_shufflevector(lo, hi, 0, 1, 2, 3, 4, 5, 6, 7);
                accO[nf] = mfma16(asbf(pu[kk]), asbf(bb), accO[nf]);
            }
    }

    const float inv = 1.f / lrun;
    float iv[4];
#pragma unroll
    for (int r = 0; r < 4; ++r) iv[r] = __shfl(inv, g * 4 + r);
#pragma unroll
    for (int nf = 0; nf < 4; ++nf)
#pragma unroll
        for (int r = 0; r < 4; ++r) {
            const int s = q0 + wq * 16 + g * 4 + r;
            AO[((size_t)b * SEQ + s) * EMBED + h * DHEAD + nf * 16 + l15] =
                f2bf(accO[nf][r] * iv[r]);
        }
}

// ---------- launch ----------
extern "C" void kernel_launch(void* const* d_in, const int* in_sizes, int n_in,
                              void* d_out, int out_size, void* d_ws, size_t ws_size,
                              hipStream_t stream)
{
    const float* x     = (const float*)d_in[0];
    const float* w_qkv = (const float*)d_in[1];
    const float* b_qkv = (const float*)d_in[2];
    const float* w_out = (const float*)d_in[3];
    const float* b_out = (const float*)d_in[4];

    // workspace (u16 elements): xb | wqt | wot | Q | K | V | Vt | AO  = 56 MB
    u16t* xb  = (u16t*)d_ws;
    u16t* wqt = xb  + (size_t)NTOK * EMBED;          // 3072*1024
    u16t* wot = wqt + (size_t)3072 * 1024;           // 1024*1024
    u16t* Qb  = wot + (size_t)1024 * 1024;
    u16t* Kb  = Qb  + (size_t)NTOK * EMBED;
    u16t* Vb  = Kb  + (size_t)NTOK * EMBED;
    u16t* Vtb = Vb  + (size_t)NTOK * EMBED;
    u16t* AOb = Vtb + (size_t)NTOK * EMBED;

    xcvt<<<2048, 256, 0, stream>>>(x, xb);
    wtrans<<<dim3(48, 16), 256, 0, stream>>>(w_qkv, wqt, 1024, 3072);
    wtrans<<<dim3(16, 16), 256, 0, stream>>>(w_out, wot, 1024, 1024);

    gemm_bf16<<<dim3(24, 32), 256, 0, stream>>>(xb, wqt, b_qkv, 3072, 1,
                                                nullptr, Qb, Kb, Vb);
    vtrans<<<dim3(32, 32), 256, 0, stream>>>(Vb, Vtb);
    attn_mfma<<<dim3(32, 32), 256, 0, stream>>>(Qb, Kb, Vtb, AOb);
    gemm_bf16<<<dim3(8, 32), 256, 0, stream>>>(AOb, wot, b_out, 1024, 0,
                                               (float*)d_out, nullptr, nullptr, nullptr);
}